// Round 1
// baseline (242.484 us; speedup 1.0000x reference)
//
#include <hip/hip_runtime.h>
#include <hip/hip_bf16.h>

// Problem constants
#define Bn 32
#define Cn 32
#define Ln 512
#define INTRA 1024
#define INTER 256
#define DCP 64
#define DDE 512
#define SCALEF 0.05f

// ---------------------------------------------------------------------------
// Prep: transpose cW1 (64x256) -> cW1T (256x64), cW2 (64x64) -> cW2T (64x64)
// ---------------------------------------------------------------------------
__global__ __launch_bounds__(256) void prep_transpose(
    const float* __restrict__ cW1, const float* __restrict__ cW2,
    float* __restrict__ cW1T, float* __restrict__ cW2T)
{
    int t = blockIdx.x * 256 + threadIdx.x;
    if (t < 64 * 256) {
        int n = t / 256, k = t % 256;
        cW1T[k * 64 + n] = cW1[t];
    }
    if (t < 64 * 64) {
        int n = t / 64, k = t % 64;
        cW2T[k * 64 + n] = cW2[t];
    }
}

// ---------------------------------------------------------------------------
// Generic batched GEMM: C[m][n] = act(A[m][k] * B[k][n] + bias)
// N fixed at 64. M % 64 == 0, K % 32 == 0.
// BIASM == 0: bias indexed by n; BIASM == 1: bias indexed by m.
// Per-batch strides sA/sB/sC (0 => shared operand).
// Block: 256 threads computing a 64x64 tile (each thread 4x4).
// ---------------------------------------------------------------------------
template <int RELU, int BIASM>
__global__ __launch_bounds__(256) void gemm_n64(
    const float* __restrict__ A, const float* __restrict__ B,
    const float* __restrict__ bias, float* __restrict__ C,
    int M, int K, long sA, long sB, long sC)
{
    const int c = blockIdx.y;
    A += (long)c * sA;
    B += (long)c * sB;
    C += (long)c * sC;
    const int m0 = blockIdx.x * 64;

    __shared__ float As[32][68];  // [k][r], padded row stride 68 (16B-aligned, bank-spread)
    __shared__ float Bs[32][64];  // [k][n]

    const int t  = threadIdx.x;
    const int tx = t % 16;        // output col group: cols tx*4 .. tx*4+3
    const int ty = t / 16;        // output row group: rows ty*4 .. ty*4+3

    // staging indices
    const int ar = t / 4;          // 0..63  A-tile row
    const int ak = (t % 4) * 8;    // 0,8,16,24 starting k within tile
    const int bk = t / 16;         // 0..15 (and +16 for second half)
    const int bn = (t % 16) * 4;   // 0..60

    float acc[4][4] = {};

    for (int k0 = 0; k0 < K; k0 += 32) {
        // --- stage A tile (64 rows x 32 k), transposed into As[k][r] ---
        {
            const float* ap = A + (long)(m0 + ar) * K + k0 + ak;
            float4 v0 = *(const float4*)(ap);
            float4 v1 = *(const float4*)(ap + 4);
            As[ak + 0][ar] = v0.x; As[ak + 1][ar] = v0.y;
            As[ak + 2][ar] = v0.z; As[ak + 3][ar] = v0.w;
            As[ak + 4][ar] = v1.x; As[ak + 5][ar] = v1.y;
            As[ak + 6][ar] = v1.z; As[ak + 7][ar] = v1.w;
        }
        // --- stage B tile (32 k x 64 n) ---
        {
            *(float4*)&Bs[bk][bn]      = *(const float4*)(B + (long)(k0 + bk) * 64 + bn);
            *(float4*)&Bs[bk + 16][bn] = *(const float4*)(B + (long)(k0 + bk + 16) * 64 + bn);
        }
        __syncthreads();

        #pragma unroll
        for (int k = 0; k < 32; ++k) {
            float4 a4 = *(const float4*)&As[k][ty * 4];
            float4 b4 = *(const float4*)&Bs[k][tx * 4];
            float av[4] = {a4.x, a4.y, a4.z, a4.w};
            float bv[4] = {b4.x, b4.y, b4.z, b4.w};
            #pragma unroll
            for (int i = 0; i < 4; ++i)
                #pragma unroll
                for (int j = 0; j < 4; ++j)
                    acc[i][j] = fmaf(av[i], bv[j], acc[i][j]);
        }
        __syncthreads();
    }

    // --- epilogue: bias + activation + coalesced store ---
    #pragma unroll
    for (int i = 0; i < 4; ++i) {
        const int m = m0 + ty * 4 + i;
        float4 o;
        float* po = (float*)&o;
        #pragma unroll
        for (int j = 0; j < 4; ++j) {
            float v = acc[i][j];
            v += BIASM ? bias[m] : bias[tx * 4 + j];
            if (RELU) v = fmaxf(v, 0.f);
            po[j] = v;
        }
        *(float4*)(C + (long)m * 64 + tx * 4) = o;
    }
}

// ---------------------------------------------------------------------------
// Fused gather + L1-score + softmax + weighted-sum + lamda blend.
// S layout: (C, INTRA, DCP) so S[c][i][:] is a contiguous 64-float row.
// Grid: (C, B). Block: 256 threads.
// ---------------------------------------------------------------------------
__global__ __launch_bounds__(256) void fuse_kernel(
    const float* __restrict__ x_loc, const int* __restrict__ indices,
    const float* __restrict__ S, const float* __restrict__ lamda1,
    const float* __restrict__ lamda2, float* __restrict__ out)
{
    const int c = blockIdx.x;
    const int b = blockIdx.y;

    __shared__ float xs[Ln];
    __shared__ int   idx[Ln];
    __shared__ float red[4][DCP];
    __shared__ float w[DCP];

    const int t = threadIdx.x;
    const float* xp = x_loc + ((long)b * Cn + c) * Ln;
    const int*   ip = indices + (long)b * Ln;
    xs[t]        = xp[t];
    xs[t + 256]  = xp[t + 256];
    idx[t]       = ip[t];
    idx[t + 256] = ip[t + 256];
    __syncthreads();

    const float* Sc = S + (long)c * INTRA * DCP;

    // Phase 1: scores[d] = sum_l |x[l] - S[c][idx[l]][d]|
    const int lane = t & 63;
    const int grp  = t >> 6;
    float s = 0.f;
    for (int l = grp; l < Ln; l += 4) {
        float g = Sc[idx[l] * DCP + lane];   // coalesced 256B per wave
        s += fabsf(xs[l] - g);
    }
    red[grp][lane] = s;
    __syncthreads();

    // Softmax over d (single wave)
    if (t < DCP) {
        float sc = red[0][t] + red[1][t] + red[2][t] + red[3][t];
        sc = -sc * (SCALEF * 0.044194173824159216f);  // 1/sqrt(512)
        float m = sc;
        #pragma unroll
        for (int o = 32; o > 0; o >>= 1) m = fmaxf(m, __shfl_xor(m, o));
        float e = __expf(sc - m);
        float ssum = e;
        #pragma unroll
        for (int o = 32; o > 0; o >>= 1) ssum += __shfl_xor(ssum, o);
        w[t] = e / ssum;
    }
    __syncthreads();

    // Phase 2: x_global[l] = sum_d w[d] * S[c][idx[l]][d]; blend with lamda
    const float lam1 = 1.f / (1.f + __expf(-lamda1[c]));
    for (int l = t; l < Ln; l += 256) {
        const float* row = Sc + (long)idx[l] * DCP;
        float acc = 0.f;
        #pragma unroll
        for (int d = 0; d < DCP; d += 4) {
            float4 g = *(const float4*)&row[d];
            acc = fmaf(g.x, w[d],     acc);
            acc = fmaf(g.y, w[d + 1], acc);
            acc = fmaf(g.z, w[d + 2], acc);
            acc = fmaf(g.w, w[d + 3], acc);
        }
        float lam = lam1 * (1.f / (1.f + __expf(-lamda2[l])));
        out[((long)b * Cn + c) * Ln + l] = acc * lam + xs[l] * (1.f - lam);
    }
}

// ---------------------------------------------------------------------------
// Launch
// ---------------------------------------------------------------------------
extern "C" void kernel_launch(void* const* d_in, const int* in_sizes, int n_in,
                              void* d_out, int out_size, void* d_ws, size_t ws_size,
                              hipStream_t stream)
{
    const float* x_loc   = (const float*)d_in[0];
    const int*   indices = (const int*)d_in[1];
    const float* map_raw = (const float*)d_in[2];
    const float* cW1     = (const float*)d_in[3];
    const float* cb1     = (const float*)d_in[4];
    const float* cW2     = (const float*)d_in[5];
    const float* cb2     = (const float*)d_in[6];
    const float* dW1     = (const float*)d_in[7];
    const float* db1     = (const float*)d_in[8];
    const float* dW2     = (const float*)d_in[9];
    const float* db2     = (const float*)d_in[10];
    const float* lamda1  = (const float*)d_in[11];
    const float* lamda2  = (const float*)d_in[12];
    float* out = (float*)d_out;

    // Workspace layout (floats)
    float* ws    = (float*)d_ws;
    float* cW1T  = ws;                        // 256*64      = 16384
    float* cW2T  = cW1T + 256 * 64;           // 64*64       = 4096
    float* P     = cW2T + 64 * 64;            // 32*1024*64  = 2097152
    float* M1    = P    + (long)Cn * INTRA * DCP;
    float* H     = M1   + (long)Cn * INTRA * DCP;   // 32*512*64 = 1048576
    float* S     = H    + (long)Cn * DDE * DCP;     // 32*1024*64

    prep_transpose<<<64, 256, 0, stream>>>(cW1, cW2, cW1T, cW2T);

    // compress-1: P[c] = relu(map_raw[c] @ cW1T + cb1)   (1024 x 64), K=256
    gemm_n64<1, 0><<<dim3(INTRA / 64, Cn), 256, 0, stream>>>(
        map_raw, cW1T, cb1, P, INTRA, INTER,
        (long)INTRA * INTER, 0, (long)INTRA * DCP);

    // compress-2: M1[c] = P[c] @ cW2T + cb2   (1024 x 64), K=64
    gemm_n64<0, 0><<<dim3(INTRA / 64, Cn), 256, 0, stream>>>(
        P, cW2T, cb2, M1, INTRA, DCP,
        (long)INTRA * DCP, 0, (long)INTRA * DCP);

    // denoise-1: H[c] = relu(dW1 @ M1[c] + db1[:,None])   (512 x 64), K=1024
    gemm_n64<1, 1><<<dim3(DDE / 64, Cn), 256, 0, stream>>>(
        dW1, M1, db1, H, DDE, INTRA,
        0, (long)INTRA * DCP, (long)DDE * DCP);

    // denoise-2: S[c] = dW2 @ H[c] + db2[:,None]   (1024 x 64), K=512
    // S[c][i][d] == map_st[c][d][i]  (transposed layout for contiguous gather)
    gemm_n64<0, 1><<<dim3(INTRA / 64, Cn), 256, 0, stream>>>(
        dW2, H, db2, S, INTRA, DDE,
        0, (long)DDE * DCP, (long)INTRA * DCP);

    fuse_kernel<<<dim3(Cn, Bn), 256, 0, stream>>>(
        x_loc, indices, S, lamda1, lamda2, out);
}

// Round 2
// 169.712 us; speedup vs baseline: 1.4288x; 1.4288x over previous
//
#include <hip/hip_runtime.h>
#include <hip/hip_bf16.h>

// Problem constants
#define Bn 32
#define Cn 32
#define Ln 512
#define INTRA 1024
#define INTER 256
#define DCP 64
#define DDE 512
#define SCALEF 0.05f

typedef __attribute__((ext_vector_type(8))) short short8;
typedef __attribute__((ext_vector_type(4))) float floatx4;

__device__ __forceinline__ short bf16_of(float f) {
    union { float f; unsigned u; } v; v.f = f;
    unsigned r = (v.u + 0x7FFFu + ((v.u >> 16) & 1u)) >> 16;
    return (short)r;
}

// ---------------------------------------------------------------------------
// Convert weights fp32 -> bf16 (layouts already [n][k] / [m][k] as needed).
// ---------------------------------------------------------------------------
__global__ __launch_bounds__(256) void prep_weights(
    const float* __restrict__ cW1, const float* __restrict__ cW2,
    const float* __restrict__ dW1, const float* __restrict__ dW2,
    short* __restrict__ cW1b, short* __restrict__ cW2b,
    short* __restrict__ dW1b, short* __restrict__ dW2b)
{
    int i = blockIdx.x * 256 + threadIdx.x;
    if (i < 64 * 256) cW1b[i] = bf16_of(cW1[i]);
    if (i < 64 * 64)  cW2b[i] = bf16_of(cW2[i]);
    if (i < DDE * INTRA) { dW1b[i] = bf16_of(dW1[i]); dW2b[i] = bf16_of(dW2[i]); }
}

// ---------------------------------------------------------------------------
// Fused compress: per block, 64 rows of map_raw[c]:
//   T  = relu(map_raw_tile @ cW1^T + cb1)        (64 x 64, stays in LDS)
//   M1 = T @ cW2^T + cb2                          (64 x 64)
// Store M1 TRANSPOSED: M1T[c][n][m]  (bf16) — the B-operand layout of denoise-1.
// Block: 256 thr = 4 waves; wave w computes rows [w*16, w*16+16) x 64 cols
// via 4 n-tiles of mfma_f32_16x16x32_bf16.
// ---------------------------------------------------------------------------
__global__ __launch_bounds__(256) void compress_fused(
    const float* __restrict__ map_raw, const short* __restrict__ cW1b,
    const float* __restrict__ cb1, const short* __restrict__ cW2b,
    const float* __restrict__ cb2, short* __restrict__ M1T)
{
    const int c  = blockIdx.y;
    const int m0 = blockIdx.x * 64;
    const float* A = map_raw + (long)c * INTRA * INTER + (long)m0 * INTER;

    __shared__ short lds[64 * 32 + 64 * 32 + 64 * 64];  // 16 KB
    short* Asb = lds;            // [m][k] stride 32
    short* Bsb = lds + 2048;     // [n][k] stride 32
    short* Tsb = lds + 4096;     // [m][k] stride 64

    const int t    = threadIdx.x;
    const int w    = t >> 6;
    const int lane = t & 63;
    const int ln   = lane & 15;
    const int quad = lane >> 4;
    const int sr = t >> 2;          // staging row 0..63
    const int sk = (t & 3) * 8;     // staging k-chunk 0,8,16,24

    floatx4 acc[4] = {};

    // prefetch k0 = 0
    float4 a0 = *(const float4*)(A + sr * INTER + sk);
    float4 a1 = *(const float4*)(A + sr * INTER + sk + 4);
    short8 bpre = *(const short8*)(cW1b + sr * INTER + sk);

    for (int k0 = 0; k0 < INTER; k0 += 32) {
        __syncthreads();
        short8 av;
        av[0] = bf16_of(a0.x); av[1] = bf16_of(a0.y);
        av[2] = bf16_of(a0.z); av[3] = bf16_of(a0.w);
        av[4] = bf16_of(a1.x); av[5] = bf16_of(a1.y);
        av[6] = bf16_of(a1.z); av[7] = bf16_of(a1.w);
        *(short8*)&Asb[sr * 32 + sk] = av;
        *(short8*)&Bsb[sr * 32 + sk] = bpre;
        __syncthreads();

        if (k0 + 32 < INTER) {   // prefetch next tile (overlaps MFMA below)
            a0 = *(const float4*)(A + sr * INTER + k0 + 32 + sk);
            a1 = *(const float4*)(A + sr * INTER + k0 + 32 + sk + 4);
            bpre = *(const short8*)(cW1b + sr * INTER + k0 + 32 + sk);
        }

        short8 af = *(const short8*)&Asb[(w * 16 + ln) * 32 + quad * 8];
        #pragma unroll
        for (int nt = 0; nt < 4; ++nt) {
            short8 bf = *(const short8*)&Bsb[(nt * 16 + ln) * 32 + quad * 8];
            acc[nt] = __builtin_amdgcn_mfma_f32_16x16x32_bf16(af, bf, acc[nt], 0, 0, 0);
        }
    }

    __syncthreads();   // phase-1 frag reads done everywhere

    // T = relu(acc + cb1) -> Tsb[m][k], bf16
    #pragma unroll
    for (int nt = 0; nt < 4; ++nt) {
        const int n = nt * 16 + ln;
        const float b = cb1[n];
        #pragma unroll
        for (int r = 0; r < 4; ++r) {
            const int m = w * 16 + quad * 4 + r;
            Tsb[m * 64 + n] = bf16_of(fmaxf(acc[nt][r] + b, 0.f));
        }
    }
    // stage cW2 [n][k] (64x64) into lds[0..4096)
    {
        const int n = t >> 2, kc = (t & 3) * 16;
        *(short8*)&lds[n * 64 + kc]     = *(const short8*)(cW2b + n * 64 + kc);
        *(short8*)&lds[n * 64 + kc + 8] = *(const short8*)(cW2b + n * 64 + kc + 8);
    }
    __syncthreads();

    floatx4 acc2[4] = {};
    #pragma unroll
    for (int ks = 0; ks < 2; ++ks) {
        short8 af = *(const short8*)&Tsb[(w * 16 + ln) * 64 + ks * 32 + quad * 8];
        #pragma unroll
        for (int nt = 0; nt < 4; ++nt) {
            short8 bf = *(const short8*)&lds[(nt * 16 + ln) * 64 + ks * 32 + quad * 8];
            acc2[nt] = __builtin_amdgcn_mfma_f32_16x16x32_bf16(af, bf, acc2[nt], 0, 0, 0);
        }
    }

    // transposed store: M1T[c][n][m0 + w*16 + quad*4 + r]
    short* out = M1T + (long)c * 64 * INTRA;
    #pragma unroll
    for (int nt = 0; nt < 4; ++nt) {
        const int n = nt * 16 + ln;
        const float b = cb2[n];
        short t0 = bf16_of(acc2[nt][0] + b);
        short t1 = bf16_of(acc2[nt][1] + b);
        short t2 = bf16_of(acc2[nt][2] + b);
        short t3 = bf16_of(acc2[nt][3] + b);
        const int m = m0 + w * 16 + quad * 4;
        *(short4*)(out + (long)n * INTRA + m) = make_short4(t0, t1, t2, t3);
    }
}

// ---------------------------------------------------------------------------
// Generic MFMA GEMM:  D[c] = act(A @ B[c] + biasM)  with
//   A  : bf16 [M][K] shared weights
//   Bt : bf16 per-c [64][K]  (B transposed, i.e. [n][k] — B-operand layout)
//   OUT_TBF16=1: store bf16 transposed [c][64][M] ; else fp32 [c][M][64]
// ---------------------------------------------------------------------------
template <int RELU, int OUT_TBF16>
__global__ __launch_bounds__(256) void gemm_mfma(
    const short* __restrict__ A, const short* __restrict__ Bt,
    const float* __restrict__ biasM, void* __restrict__ Cout,
    int M, int K)
{
    const int c  = blockIdx.y;
    const int m0 = blockIdx.x * 64;
    const short* Bc = Bt + (long)c * 64 * K;

    __shared__ short Asb[64 * 32];
    __shared__ short Bsb[64 * 32];

    const int t    = threadIdx.x;
    const int w    = t >> 6;
    const int lane = t & 63;
    const int ln   = lane & 15;
    const int quad = lane >> 4;
    const int sr = t >> 2;
    const int sk = (t & 3) * 8;

    floatx4 acc[4] = {};
    short8 apre = *(const short8*)(A + (long)(m0 + sr) * K + sk);
    short8 bpre = *(const short8*)(Bc + (long)sr * K + sk);

    for (int k0 = 0; k0 < K; k0 += 32) {
        __syncthreads();
        *(short8*)&Asb[sr * 32 + sk] = apre;
        *(short8*)&Bsb[sr * 32 + sk] = bpre;
        __syncthreads();
        const int kn = k0 + 32;
        if (kn < K) {
            apre = *(const short8*)(A + (long)(m0 + sr) * K + kn + sk);
            bpre = *(const short8*)(Bc + (long)sr * K + kn + sk);
        }
        short8 af = *(const short8*)&Asb[(w * 16 + ln) * 32 + quad * 8];
        #pragma unroll
        for (int nt = 0; nt < 4; ++nt) {
            short8 bf = *(const short8*)&Bsb[(nt * 16 + ln) * 32 + quad * 8];
            acc[nt] = __builtin_amdgcn_mfma_f32_16x16x32_bf16(af, bf, acc[nt], 0, 0, 0);
        }
    }

    float bm[4];
    #pragma unroll
    for (int r = 0; r < 4; ++r) bm[r] = biasM[m0 + w * 16 + quad * 4 + r];

    if (OUT_TBF16) {
        short* out = (short*)Cout + (long)c * 64 * M;
        #pragma unroll
        for (int nt = 0; nt < 4; ++nt) {
            const int n = nt * 16 + ln;
            short t0, t1, t2, t3;
            float v0 = acc[nt][0] + bm[0], v1 = acc[nt][1] + bm[1];
            float v2 = acc[nt][2] + bm[2], v3 = acc[nt][3] + bm[3];
            if (RELU) { v0 = fmaxf(v0, 0.f); v1 = fmaxf(v1, 0.f);
                        v2 = fmaxf(v2, 0.f); v3 = fmaxf(v3, 0.f); }
            t0 = bf16_of(v0); t1 = bf16_of(v1); t2 = bf16_of(v2); t3 = bf16_of(v3);
            const int m = m0 + w * 16 + quad * 4;
            *(short4*)(out + (long)n * M + m) = make_short4(t0, t1, t2, t3);
        }
    } else {
        float* out = (float*)Cout + (long)c * (long)M * 64;
        #pragma unroll
        for (int nt = 0; nt < 4; ++nt) {
            const int n = nt * 16 + ln;
            #pragma unroll
            for (int r = 0; r < 4; ++r) {
                float v = acc[nt][r] + bm[r];
                if (RELU) v = fmaxf(v, 0.f);
                out[(long)(m0 + w * 16 + quad * 4 + r) * 64 + n] = v;
            }
        }
    }
}

// ---------------------------------------------------------------------------
// Fused gather + L1-score + softmax + weighted-sum + lamda blend (unchanged).
// S layout: (C, INTRA, DCP) fp32.
// ---------------------------------------------------------------------------
__global__ __launch_bounds__(256) void fuse_kernel(
    const float* __restrict__ x_loc, const int* __restrict__ indices,
    const float* __restrict__ S, const float* __restrict__ lamda1,
    const float* __restrict__ lamda2, float* __restrict__ out)
{
    const int c = blockIdx.x;
    const int b = blockIdx.y;

    __shared__ float xs[Ln];
    __shared__ int   idx[Ln];
    __shared__ float red[4][DCP];
    __shared__ float w[DCP];

    const int t = threadIdx.x;
    const float* xp = x_loc + ((long)b * Cn + c) * Ln;
    const int*   ip = indices + (long)b * Ln;
    xs[t]        = xp[t];
    xs[t + 256]  = xp[t + 256];
    idx[t]       = ip[t];
    idx[t + 256] = ip[t + 256];
    __syncthreads();

    const float* Sc = S + (long)c * INTRA * DCP;

    const int lane = t & 63;
    const int grp  = t >> 6;
    float s = 0.f;
    for (int l = grp; l < Ln; l += 4) {
        float g = Sc[idx[l] * DCP + lane];
        s += fabsf(xs[l] - g);
    }
    red[grp][lane] = s;
    __syncthreads();

    if (t < DCP) {
        float sc = red[0][t] + red[1][t] + red[2][t] + red[3][t];
        sc = -sc * (SCALEF * 0.044194173824159216f);
        float m = sc;
        #pragma unroll
        for (int o = 32; o > 0; o >>= 1) m = fmaxf(m, __shfl_xor(m, o));
        float e = __expf(sc - m);
        float ssum = e;
        #pragma unroll
        for (int o = 32; o > 0; o >>= 1) ssum += __shfl_xor(ssum, o);
        w[t] = e / ssum;
    }
    __syncthreads();

    const float lam1 = 1.f / (1.f + __expf(-lamda1[c]));
    for (int l = t; l < Ln; l += 256) {
        const float* row = Sc + (long)idx[l] * DCP;
        float acc = 0.f;
        #pragma unroll
        for (int d = 0; d < DCP; d += 4) {
            float4 g = *(const float4*)&row[d];
            acc = fmaf(g.x, w[d],     acc);
            acc = fmaf(g.y, w[d + 1], acc);
            acc = fmaf(g.z, w[d + 2], acc);
            acc = fmaf(g.w, w[d + 3], acc);
        }
        float lam = lam1 * (1.f / (1.f + __expf(-lamda2[l])));
        out[((long)b * Cn + c) * Ln + l] = acc * lam + xs[l] * (1.f - lam);
    }
}

// ---------------------------------------------------------------------------
// Launch
// ---------------------------------------------------------------------------
extern "C" void kernel_launch(void* const* d_in, const int* in_sizes, int n_in,
                              void* d_out, int out_size, void* d_ws, size_t ws_size,
                              hipStream_t stream)
{
    const float* x_loc   = (const float*)d_in[0];
    const int*   indices = (const int*)d_in[1];
    const float* map_raw = (const float*)d_in[2];
    const float* cW1     = (const float*)d_in[3];
    const float* cb1     = (const float*)d_in[4];
    const float* cW2     = (const float*)d_in[5];
    const float* cb2     = (const float*)d_in[6];
    const float* dW1     = (const float*)d_in[7];
    const float* db1     = (const float*)d_in[8];
    const float* dW2     = (const float*)d_in[9];
    const float* db2     = (const float*)d_in[10];
    const float* lamda1  = (const float*)d_in[11];
    const float* lamda2  = (const float*)d_in[12];
    float* out = (float*)d_out;

    short* wsS  = (short*)d_ws;
    short* cW1b = wsS;                       // 64*256   = 16384
    short* cW2b = cW1b + 16384;              // 64*64    = 4096
    short* dW1b = cW2b + 4096;               // 512*1024 = 524288
    short* dW2b = dW1b + 524288;             // 1024*512 = 524288
    short* M1T  = dW2b + 524288;             // 32*64*1024 = 2097152
    short* HT   = M1T + 2097152;             // 32*64*512  = 1048576
    float* S    = (float*)(HT + 1048576);    // 32*1024*64 fp32

    prep_weights<<<2048, 256, 0, stream>>>(cW1, cW2, dW1, dW2,
                                           cW1b, cW2b, dW1b, dW2b);

    compress_fused<<<dim3(INTRA / 64, Cn), 256, 0, stream>>>(
        map_raw, cW1b, cb1, cW2b, cb2, M1T);

    // denoise-1: HT[c] = relu(dW1 @ M1[c] + db1) stored transposed bf16
    gemm_mfma<1, 1><<<dim3(DDE / 64, Cn), 256, 0, stream>>>(
        dW1b, M1T, db1, (void*)HT, DDE, INTRA);

    // denoise-2: S[c] = dW2 @ H[c] + db2, fp32 (INTRA x DCP) per c
    gemm_mfma<0, 0><<<dim3(INTRA / 64, Cn), 256, 0, stream>>>(
        dW2b, HT, db2, (void*)S, INTRA, DDE);

    fuse_kernel<<<dim3(Cn, Bn), 256, 0, stream>>>(
        x_loc, indices, S, lamda1, lamda2, out);
}